// Round 2
// baseline (585.635 us; speedup 1.0000x reference)
//
#include <hip/hip_runtime.h>

// AttentionLayer: N=8, L=1024, D_MODEL=1024, H=16, d_head=64.
// out  = softmax(QK^T/8)V reshaped   (8,1024,1024) fp32
// attn = mean over heads of softmax  (8,1024,1024) fp32, concatenated after out.
//
// 3 kernels: k0 convert fp32->bf16 (row-major + transposed copies in ws),
// k1 softmax denominators (no max-subtraction needed: scores <= ~15),
// k2 main attention with mfma_f32_16x16x32_bf16.
// ws usage: 16MB bN + 16MB bT + 512KB inv_rs = ~34MB.
//
// R1 fix: k2 K-fragment prefetch was missing the +nh*DH head offset (all
// heads>0 scored against head 0's K). Also: inv_rs hoisted to registers.

#define NB 8
#define LQ 1024
#define DM 1024
#define NH 16
#define DH 64

typedef __attribute__((ext_vector_type(4))) float f32x4;
typedef __attribute__((ext_vector_type(8))) short bf16x8;
typedef __attribute__((ext_vector_type(4))) short bf16x4;

__device__ inline short f2bf(float f){
  unsigned u = __builtin_bit_cast(unsigned, f);
  u += 0x7fffu + ((u >> 16) & 1u);   // RNE (inputs finite)
  return (short)(u >> 16);
}

// ---------------- k0: fp32 -> bf16, straight copy + transposed copy ----------
__global__ __launch_bounds__(256) void k0_convert(const float* __restrict__ in,
                                                  short* __restrict__ bN,
                                                  short* __restrict__ bT){
  __shared__ short tile[32][36];          // +4 pad keeps 8B alignment, breaks conflicts
  int b  = blockIdx.x;
  int n  = b >> 10;
  int lt = (b >> 5) & 31;
  int dt = b & 31;
  int r  = threadIdx.x >> 3;              // 0..31
  int c4 = (threadIdx.x & 7) << 2;        // 0,4,...,28
  size_t src = ((size_t)(n*LQ + lt*32 + r))*DM + dt*32 + c4;
  f32x4 f = *(const f32x4*)(in + src);
  short s0 = f2bf(f.x), s1 = f2bf(f.y), s2 = f2bf(f.z), s3 = f2bf(f.w);
  bf16x4 pk = {s0, s1, s2, s3};
  *(bf16x4*)(bN + src) = pk;
  tile[c4+0][r] = s0; tile[c4+1][r] = s1; tile[c4+2][r] = s2; tile[c4+3][r] = s3;
  __syncthreads();
  bf16x4 t = *(const bf16x4*)(&tile[r][c4]);
  size_t dst = ((size_t)(n*DM + dt*32 + r))*LQ + lt*32 + c4;
  *(bf16x4*)(bT + dst) = t;
}

// ---------------- k1: inv softmax denominators ------------------------------
// block: (n, h, 64 q-rows); each wave owns one 16-q tile, loops full s.
// St = K.Q^T via mfma: A=K (m=s, k=d), B=Q (n=q, k=d). C: col(lane&15)=q.
__global__ __launch_bounds__(256) void k1_rowsum(const short* __restrict__ bN,
                                                 float* __restrict__ inv_rs){
  int b  = blockIdx.x;
  int n  = b & 7;                // XCD swizzle: same n -> same XCD L2
  int h  = (b >> 3) & 15;
  int qb = b >> 7;               // 0..15
  int lane = threadIdx.x & 63;
  int w    = threadIdx.x >> 6;
  int l16  = lane & 15;
  int quad = lane >> 4;
  int q0 = qb*64 + w*16;

  const short* qp = bN + ((size_t)(n*LQ + q0 + l16))*DM + h*DH + quad*8;
  bf16x8 qf0 = *(const bf16x8*)qp;
  bf16x8 qf1 = *(const bf16x8*)(qp + 32);

  float rs = 0.f;
  for (int s0 = 0; s0 < LQ; s0 += 16){
    const short* kp = bN + ((size_t)(n*LQ + s0 + l16))*DM + h*DH + quad*8;
    bf16x8 kf0 = *(const bf16x8*)kp;
    bf16x8 kf1 = *(const bf16x8*)(kp + 32);
    f32x4 st = {0.f, 0.f, 0.f, 0.f};
    st = __builtin_amdgcn_mfma_f32_16x16x32_bf16(kf0, qf0, st, 0, 0, 0);
    st = __builtin_amdgcn_mfma_f32_16x16x32_bf16(kf1, qf1, st, 0, 0, 0);
    rs += __expf(st[0]*0.125f) + __expf(st[1]*0.125f)
        + __expf(st[2]*0.125f) + __expf(st[3]*0.125f);
  }
  rs += __shfl_xor(rs, 16);      // reduce across quads (same q column)
  rs += __shfl_xor(rs, 32);
  if (lane < 16)
    inv_rs[((size_t)(n*NH + h)) * LQ + q0 + lane] = 1.0f / rs;
}

// ---------------- k2: main attention ----------------------------------------
// block: (n, 16 q-rows), 4 waves. Per s-chunk of 64: wave w = s-slice for St,
// d-tile for PV. P normalized immediately (inv_rs from k1), bounced via LDS
// into A-layout; V B-frags contiguous from transposed bT.
__global__ __launch_bounds__(256, 3) void k2_attn(const short* __restrict__ bN,
                                                  const short* __restrict__ bT,
                                                  const float* __restrict__ inv_rs,
                                                  float* __restrict__ out,
                                                  float* __restrict__ attn){
  __shared__ short Plds[16*72];  // 16 q-rows x 64 s (+8 pad): 16B-aligned rows
  int lane = threadIdx.x & 63;
  int w    = threadIdx.x >> 6;
  int l16  = lane & 15;
  int quad = lane >> 4;
  int n  = blockIdx.x & 7;       // XCD swizzle
  int qb = blockIdx.x >> 3;      // 0..63
  int q0 = qb*16;

  const f32x4 vzero = {0.f, 0.f, 0.f, 0.f};
  f32x4 oacc[16];
  #pragma unroll
  for (int h = 0; h < 16; ++h) oacc[h] = vzero;

  // hoist softmax normalizers: per-lane only l16's q matters
  float ir[16];
  #pragma unroll
  for (int h = 0; h < 16; ++h)
    ir[h] = inv_rs[((size_t)(n*NH + h)) * LQ + q0 + l16];

  const short* qbase = bN + ((size_t)(n*LQ + q0 + l16))*DM + quad*8;
  // preload (c=0, h=0) K/Q fragments
  bf16x8 qf0 = *(const bf16x8*)(qbase);
  bf16x8 qf1 = *(const bf16x8*)(qbase + 32);
  const short* kp0 = bN + ((size_t)(n*LQ + w*16 + l16))*DM + quad*8;
  bf16x8 kf0 = *(const bf16x8*)(kp0);
  bf16x8 kf1 = *(const bf16x8*)(kp0 + 32);

  for (int c = 0; c < 16; ++c){
    int s0 = c*64;
    f32x4 aacc = vzero;
    #pragma unroll
    for (int h = 0; h < 16; ++h){
      // V fragments (transposed layout: rows = d, contiguous s) — issue early
      const short* vp = bT + ((size_t)(n*DM + h*DH + w*16 + l16))*LQ + s0 + quad*8;
      bf16x8 vf0 = *(const bf16x8*)vp;         // k-step 0: s-local 0..31
      bf16x8 vf1 = *(const bf16x8*)(vp + 32);  // k-step 1: s-local 32..63
      // scores: St (m = s-local(w*16+quad*4+r), n = q(l16))
      f32x4 st = vzero;
      st = __builtin_amdgcn_mfma_f32_16x16x32_bf16(kf0, qf0, st, 0, 0, 0);
      st = __builtin_amdgcn_mfma_f32_16x16x32_bf16(kf1, qf1, st, 0, 0, 0);
      float p0 = __expf(st[0]*0.125f) * ir[h];
      float p1 = __expf(st[1]*0.125f) * ir[h];
      float p2 = __expf(st[2]*0.125f) * ir[h];
      float p3 = __expf(st[3]*0.125f) * ir[h];
      aacc[0] += p0; aacc[1] += p1; aacc[2] += p2; aacc[3] += p3;
      bf16x4 pk = {f2bf(p0), f2bf(p1), f2bf(p2), f2bf(p3)};
      *(bf16x4*)(&Plds[l16*72 + w*16 + quad*4]) = pk;
      // prefetch next (head, chunk) K/Q before the barrier
      int nh  = (h + 1) & 15;
      int ncs = (h == 15) ? ((c < 15) ? s0 + 64 : s0) : s0;
      const short* kp = bN + ((size_t)(n*LQ + ncs + w*16 + l16))*DM + nh*DH + quad*8;
      bf16x8 nkf0 = *(const bf16x8*)kp;
      bf16x8 nkf1 = *(const bf16x8*)(kp + 32);
      bf16x8 nqf0 = *(const bf16x8*)(qbase + nh*DH);
      bf16x8 nqf1 = *(const bf16x8*)(qbase + nh*DH + 32);
      __syncthreads();
      // PV: A = P (m=q(l16), k=s-local), B = V (n=d(l16), k=s-local)
      bf16x8 a0 = *(const bf16x8*)(&Plds[l16*72 + quad*8]);
      bf16x8 a1 = *(const bf16x8*)(&Plds[l16*72 + 32 + quad*8]);
      oacc[h] = __builtin_amdgcn_mfma_f32_16x16x32_bf16(a0, vf0, oacc[h], 0, 0, 0);
      oacc[h] = __builtin_amdgcn_mfma_f32_16x16x32_bf16(a1, vf1, oacc[h], 0, 0, 0);
      __syncthreads();             // protect Plds before next head rewrites it
      kf0 = nkf0; kf1 = nkf1; qf0 = nqf0; qf1 = nqf1;
    }
    // attn (head-mean) for this s-chunk: row q0+l16, cols s0+w*16+quad*4..+3
    f32x4 av = {aacc[0]*0.0625f, aacc[1]*0.0625f, aacc[2]*0.0625f, aacc[3]*0.0625f};
    *(f32x4*)(attn + ((size_t)(n*LQ + q0 + l16)) * LQ + s0 + w*16 + quad*4) = av;
  }
  // O write: row q0+quad*4+r, col h*64 + w*16 + l16
  #pragma unroll
  for (int h = 0; h < 16; ++h){
    float* op = out + ((size_t)(n*LQ + q0 + quad*4)) * DM + h*DH + w*16 + l16;
    op[0]      = oacc[h][0];
    op[DM]     = oacc[h][1];
    op[2*DM]   = oacc[h][2];
    op[3*DM]   = oacc[h][3];
  }
}

extern "C" void kernel_launch(void* const* d_in, const int* in_sizes, int n_in,
                              void* d_out, int out_size, void* d_ws, size_t ws_size,
                              hipStream_t stream){
  const float* in = (const float*)d_in[0];
  float* out  = (float*)d_out;
  float* attn = out + (size_t)NB*LQ*DM;
  short* bN = (short*)d_ws;
  short* bT = bN + (size_t)NB*LQ*DM;
  float* inv_rs = (float*)(bT + (size_t)NB*LQ*DM);   // needs ~34MB of ws total

  k0_convert<<<dim3(8192), dim3(256), 0, stream>>>(in, bN, bT);
  k1_rowsum <<<dim3(2048), dim3(256), 0, stream>>>(bN, inv_rs);
  k2_attn   <<<dim3(512),  dim3(256), 0, stream>>>(bN, bT, inv_rs, out, attn);
}

// Round 3
// 580.874 us; speedup vs baseline: 1.0082x; 1.0082x over previous
//
#include <hip/hip_runtime.h>

// AttentionLayer: N=8, L=1024, D_MODEL=1024, H=16, d_head=64.
// out  = softmax(QK^T/8)V reshaped   (8,1024,1024) fp32
// attn = mean over heads of softmax  (8,1024,1024) fp32, after out.
//
// R3: 2 kernels. k0 converts fp32->bf16 (row-major bN + d-major bT).
// k2 fuses the softmax-denominator pre-pass (was k1) and runs the main
// attention with 2 barriers per 64-s chunk (was 32): phase A computes P for
// ALL 16 heads into LDS, one barrier, phase B does all 16 heads' PV.
// attn output bounced through LDS for full-line coalesced stores.
// ws: 32 MB (bN + bT).

#define NB 8
#define LQ 1024
#define DM 1024
#define NH 16
#define DH 64
#define SP 72           // Plds row stride (shorts): 144 B, 16B-aligned, breaks pow2
#define AP 68           // attn_lds row stride (floats)

typedef __attribute__((ext_vector_type(4))) float f32x4;
typedef __attribute__((ext_vector_type(8))) short bf16x8;
typedef __attribute__((ext_vector_type(4))) short bf16x4;

__device__ inline short f2bf(float f){
  unsigned u = __builtin_bit_cast(unsigned, f);
  u += 0x7fffu + ((u >> 16) & 1u);   // RNE (inputs finite)
  return (short)(u >> 16);
}

// ---------------- k0: fp32 -> bf16, straight copy + transposed copy ----------
__global__ __launch_bounds__(256) void k0_convert(const float* __restrict__ in,
                                                  short* __restrict__ bN,
                                                  short* __restrict__ bT){
  __shared__ short tile[32][36];
  int b  = blockIdx.x;
  int n  = b >> 10;
  int lt = (b >> 5) & 31;
  int dt = b & 31;
  int r  = threadIdx.x >> 3;
  int c4 = (threadIdx.x & 7) << 2;
  size_t src = ((size_t)(n*LQ + lt*32 + r))*DM + dt*32 + c4;
  f32x4 f = *(const f32x4*)(in + src);
  short s0 = f2bf(f.x), s1 = f2bf(f.y), s2 = f2bf(f.z), s3 = f2bf(f.w);
  bf16x4 pk = {s0, s1, s2, s3};
  *(bf16x4*)(bN + src) = pk;
  tile[c4+0][r] = s0; tile[c4+1][r] = s1; tile[c4+2][r] = s2; tile[c4+3][r] = s3;
  __syncthreads();
  bf16x4 t = *(const bf16x4*)(&tile[r][c4]);
  size_t dst = ((size_t)(n*DM + dt*32 + r))*LQ + lt*32 + c4;
  *(bf16x4*)(bT + dst) = t;
}

// ---------------- k2: fused rs pre-pass + attention --------------------------
// block: (n, 16 q-rows), 4 waves. St C-layout: col(l16)=q, row(quad*4+r)=s.
__global__ __launch_bounds__(256, 3) void k2_attn(const short* __restrict__ bN,
                                                  const short* __restrict__ bT,
                                                  float* __restrict__ out,
                                                  float* __restrict__ attn){
  __shared__ short Plds[NH*16*SP];      // 36864 B: P[h][q][s_local 0..63]
  __shared__ float attn_lds[16*AP];     // 4352 B
  __shared__ float rs_lds[NH*16];       // 1024 B: rowsums then reciprocals
  int lane = threadIdx.x & 63;
  int w    = threadIdx.x >> 6;
  int l16  = lane & 15;
  int quad = lane >> 4;
  int n  = blockIdx.x & 7;              // XCD swizzle
  int q0 = (blockIdx.x >> 3) * 16;

  rs_lds[threadIdx.x] = 0.f;
  __syncthreads();

  const short* qbase = bN + ((size_t)(n*LQ + q0 + l16))*DM + quad*8;
  const f32x4 vzero = {0.f, 0.f, 0.f, 0.f};

  // ---- pre-pass: softmax denominators; wave w covers s in [w*256, w*256+256)
  for (int h = 0; h < NH; ++h){
    bf16x8 qf0 = *(const bf16x8*)(qbase + h*DH);
    bf16x8 qf1 = *(const bf16x8*)(qbase + h*DH + 32);
    float rsum = 0.f;
    #pragma unroll 4
    for (int ss = 0; ss < 16; ++ss){
      const short* kp = bN + ((size_t)(n*LQ + w*256 + ss*16 + l16))*DM + h*DH + quad*8;
      bf16x8 kf0 = *(const bf16x8*)kp;
      bf16x8 kf1 = *(const bf16x8*)(kp + 32);
      f32x4 st = vzero;
      st = __builtin_amdgcn_mfma_f32_16x16x32_bf16(kf0, qf0, st, 0, 0, 0);
      st = __builtin_amdgcn_mfma_f32_16x16x32_bf16(kf1, qf1, st, 0, 0, 0);
      rsum += __expf(st[0]*0.125f) + __expf(st[1]*0.125f)
            + __expf(st[2]*0.125f) + __expf(st[3]*0.125f);
    }
    rsum += __shfl_xor(rsum, 16);
    rsum += __shfl_xor(rsum, 32);
    if (lane < 16) atomicAdd(&rs_lds[h*16 + l16], rsum);
  }
  __syncthreads();
  float v = rs_lds[threadIdx.x];
  __syncthreads();
  rs_lds[threadIdx.x] = 1.0f / v;
  __syncthreads();
  float ir[NH];
  #pragma unroll
  for (int h = 0; h < NH; ++h) ir[h] = rs_lds[h*16 + l16];

  f32x4 oacc[NH];
  #pragma unroll
  for (int h = 0; h < NH; ++h) oacc[h] = vzero;

  // ---- main loop over s-chunks of 64
  for (int c = 0; c < 16; ++c){
    int sw = c*64 + w*16;               // this wave's s-slice
    f32x4 aacc = vzero;
    // phase A: scores+exp for all heads -> Plds
    #pragma unroll
    for (int h = 0; h < NH; ++h){
      const short* kp = bN + ((size_t)(n*LQ + sw + l16))*DM + h*DH + quad*8;
      bf16x8 kf0 = *(const bf16x8*)kp;
      bf16x8 kf1 = *(const bf16x8*)(kp + 32);
      bf16x8 qf0 = *(const bf16x8*)(qbase + h*DH);
      bf16x8 qf1 = *(const bf16x8*)(qbase + h*DH + 32);
      f32x4 st = vzero;
      st = __builtin_amdgcn_mfma_f32_16x16x32_bf16(kf0, qf0, st, 0, 0, 0);
      st = __builtin_amdgcn_mfma_f32_16x16x32_bf16(kf1, qf1, st, 0, 0, 0);
      float p0 = __expf(st[0]*0.125f) * ir[h];
      float p1 = __expf(st[1]*0.125f) * ir[h];
      float p2 = __expf(st[2]*0.125f) * ir[h];
      float p3 = __expf(st[3]*0.125f) * ir[h];
      aacc[0] += p0; aacc[1] += p1; aacc[2] += p2; aacc[3] += p3;
      bf16x4 pk = {f2bf(p0), f2bf(p1), f2bf(p2), f2bf(p3)};
      *(bf16x4*)(&Plds[(h*16 + l16)*SP + w*16 + quad*4]) = pk;
    }
    // attn head-mean tile for this chunk: q=l16, s_local=w*16+quad*4..+3
    f32x4 am = {aacc[0]*0.0625f, aacc[1]*0.0625f, aacc[2]*0.0625f, aacc[3]*0.0625f};
    *(f32x4*)(&attn_lds[l16*AP + w*16 + quad*4]) = am;
    __syncthreads();
    // attn writeout: full 256B-contiguous rows (kills write amplification)
    {
      int row = threadIdx.x >> 4;
      int c4  = (threadIdx.x & 15) << 2;
      f32x4 av = *(const f32x4*)(&attn_lds[row*AP + c4]);
      *(f32x4*)(attn + ((size_t)(n*LQ + q0 + row))*LQ + c*64 + c4) = av;
    }
    // phase B: PV for all heads; this wave's d-slice = w*16
    #pragma unroll
    for (int h = 0; h < NH; ++h){
      const short* vp = bT + ((size_t)(n*DM + h*DH + w*16 + l16))*LQ + c*64 + quad*8;
      bf16x8 vf0 = *(const bf16x8*)vp;
      bf16x8 vf1 = *(const bf16x8*)(vp + 32);
      bf16x8 a0 = *(const bf16x8*)(&Plds[(h*16 + l16)*SP + quad*8]);
      bf16x8 a1 = *(const bf16x8*)(&Plds[(h*16 + l16)*SP + 32 + quad*8]);
      oacc[h] = __builtin_amdgcn_mfma_f32_16x16x32_bf16(a0, vf0, oacc[h], 0, 0, 0);
      oacc[h] = __builtin_amdgcn_mfma_f32_16x16x32_bf16(a1, vf1, oacc[h], 0, 0, 0);
    }
    __syncthreads();                    // Plds/attn_lds reused next chunk
  }
  // O store: row q0+quad*4+r, col h*64 + w*16 + l16 (64B-coalesced per quad)
  #pragma unroll
  for (int h = 0; h < NH; ++h){
    float* op = out + ((size_t)(n*LQ + q0 + quad*4))*DM + h*DH + w*16 + l16;
    op[0]    = oacc[h][0];
    op[DM]   = oacc[h][1];
    op[2*DM] = oacc[h][2];
    op[3*DM] = oacc[h][3];
  }
}

extern "C" void kernel_launch(void* const* d_in, const int* in_sizes, int n_in,
                              void* d_out, int out_size, void* d_ws, size_t ws_size,
                              hipStream_t stream){
  const float* in = (const float*)d_in[0];
  float* out  = (float*)d_out;
  float* attn = out + (size_t)NB*LQ*DM;
  short* bN = (short*)d_ws;
  short* bT = bN + (size_t)NB*LQ*DM;

  k0_convert<<<dim3(8192), dim3(256), 0, stream>>>(in, bN, bT);
  k2_attn   <<<dim3(512),  dim3(256), 0, stream>>>(bN, bT, out, attn);
}

// Round 4
// 434.195 us; speedup vs baseline: 1.3488x; 1.3378x over previous
//
#include <hip/hip_runtime.h>

// AttentionLayer: N=8, L=1024, D_MODEL=1024, H=16, d_head=64.
// out  = softmax(QK^T/8)V reshaped   (8,1024,1024) fp32
// attn = mean over heads of softmax  (8,1024,1024) fp32, after out.
//
// R4: fix the parallelism bug. R3 had 2048 waves total (2/SIMD) — grid-capped
// at 25% occupancy, latency-bound everywhere. Now: block = 1024 thr = 16
// waves, ONE WAVE PER HEAD, block owns (n, 16 q). 8192 waves = 8/SIMD worth
// of wave-units; VGPR-limited to 1 block/CU -> 16 waves/CU (50%).
// Each wave: private rowsum pre-pass (shuffle-reduced, register ir), main
// loop with wave-private LDS P-bounce (no barriers), PV into regs.
// Only cross-wave sync: attn head-mean staging, 2 barriers per 64-s window.
// ws: 32 MB (bN row-major + bT d-major bf16 copies).

#define NB 8
#define LQ 1024
#define DM 1024
#define NH 16
#define DH 64
#define PW 40           // P32 row stride (shorts): 80 B, breaks pow2
#define AW 68           // attn stage row stride (floats): 272 B

typedef __attribute__((ext_vector_type(4))) float f32x4;
typedef __attribute__((ext_vector_type(8))) short bf16x8;
typedef __attribute__((ext_vector_type(4))) short bf16x4;

__device__ inline short f2bf(float f){
  unsigned u = __builtin_bit_cast(unsigned, f);
  u += 0x7fffu + ((u >> 16) & 1u);   // RNE (inputs finite)
  return (short)(u >> 16);
}

// ---------------- k0: fp32 -> bf16, straight copy + transposed copy ----------
__global__ __launch_bounds__(256) void k0_convert(const float* __restrict__ in,
                                                  short* __restrict__ bN,
                                                  short* __restrict__ bT){
  __shared__ short tile[32][36];
  int b  = blockIdx.x;
  int n  = b >> 10;
  int lt = (b >> 5) & 31;
  int dt = b & 31;
  int r  = threadIdx.x >> 3;
  int c4 = (threadIdx.x & 7) << 2;
  size_t src = ((size_t)(n*LQ + lt*32 + r))*DM + dt*32 + c4;
  f32x4 f = *(const f32x4*)(in + src);
  short s0 = f2bf(f.x), s1 = f2bf(f.y), s2 = f2bf(f.z), s3 = f2bf(f.w);
  bf16x4 pk = {s0, s1, s2, s3};
  *(bf16x4*)(bN + src) = pk;
  tile[c4+0][r] = s0; tile[c4+1][r] = s1; tile[c4+2][r] = s2; tile[c4+3][r] = s3;
  __syncthreads();
  bf16x4 t = *(const bf16x4*)(&tile[r][c4]);
  size_t dst = ((size_t)(n*DM + dt*32 + r))*LQ + lt*32 + c4;
  *(bf16x4*)(bT + dst) = t;
}

// ---------------- k2: one wave per head ---------------------------------------
__global__ __launch_bounds__(1024) void k2_attn(const short* __restrict__ bN,
                                                const short* __restrict__ bT,
                                                float* __restrict__ out,
                                                float* __restrict__ attn){
  __shared__ float astage[NH*16*AW];    // 69632 B: per-wave attn window tiles
  __shared__ short P32[NH*16*PW];       // 20480 B: per-wave P bounce (16q x 32s)
  int tid  = threadIdx.x;
  int lane = tid & 63;
  int w    = tid >> 6;                  // wave id == head id
  int l16  = lane & 15;
  int quad = lane >> 4;
  int n  = blockIdx.x & 7;              // XCD swizzle
  int q0 = (blockIdx.x >> 3) << 4;

  const float CE = 0.1803368801111244f; // 0.125 * log2(e)
  const f32x4 vzero = {0.f, 0.f, 0.f, 0.f};

  // Q fragments for this head (persist)
  const short* qp = bN + ((size_t)(n*LQ + q0 + l16))*DM + w*DH + quad*8;
  bf16x8 qf0 = *(const bf16x8*)qp;
  bf16x8 qf1 = *(const bf16x8*)(qp + 32);

  const short* kbase = bN + ((size_t)(n*LQ + l16))*DM + w*DH + quad*8;
  const short* vbase = bT + ((size_t)(n*DM + w*DH + l16))*LQ + quad*8;

  // ---- pre-pass: softmax denominator for q = l16 (wave-private) ----
  float rsum = 0.f;
  #pragma unroll 4
  for (int ss = 0; ss < 64; ++ss){
    const short* kp = kbase + (size_t)ss*16*DM;
    bf16x8 kf0 = *(const bf16x8*)kp;
    bf16x8 kf1 = *(const bf16x8*)(kp + 32);
    f32x4 st = vzero;
    st = __builtin_amdgcn_mfma_f32_16x16x32_bf16(kf0, qf0, st, 0, 0, 0);
    st = __builtin_amdgcn_mfma_f32_16x16x32_bf16(kf1, qf1, st, 0, 0, 0);
    rsum += __builtin_amdgcn_exp2f(st[0]*CE) + __builtin_amdgcn_exp2f(st[1]*CE)
          + __builtin_amdgcn_exp2f(st[2]*CE) + __builtin_amdgcn_exp2f(st[3]*CE);
  }
  rsum += __shfl_xor(rsum, 16);
  rsum += __shfl_xor(rsum, 32);
  float ir  = 1.0f / rsum;              // normalizer for q = l16
  float irs = ir * 0.0625f;             // folded 1/NH for attn

  f32x4 oacc[4];
  #pragma unroll
  for (int dt = 0; dt < 4; ++dt) oacc[dt] = vzero;

  short* Pmine = &P32[w*16*PW];
  float* Amine = &astage[(size_t)w*16*AW];

  // ---- main loop: 16 windows of 64 s ----
  for (int win = 0; win < 16; ++win){
    f32x4 av[4];
    #pragma unroll
    for (int half = 0; half < 2; ++half){
      // two 16-s QK steps fill P32 (16q x 32s), wave-private
      #pragma unroll
      for (int sub = 0; sub < 2; ++sub){
        int sl = half*32 + sub*16;                 // window-local s
        const short* kp = kbase + (size_t)(win*64 + sl)*DM;
        bf16x8 kf0 = *(const bf16x8*)kp;
        bf16x8 kf1 = *(const bf16x8*)(kp + 32);
        f32x4 st = vzero;
        st = __builtin_amdgcn_mfma_f32_16x16x32_bf16(kf0, qf0, st, 0, 0, 0);
        st = __builtin_amdgcn_mfma_f32_16x16x32_bf16(kf1, qf1, st, 0, 0, 0);
        float e0 = __builtin_amdgcn_exp2f(st[0]*CE);
        float e1 = __builtin_amdgcn_exp2f(st[1]*CE);
        float e2 = __builtin_amdgcn_exp2f(st[2]*CE);
        float e3 = __builtin_amdgcn_exp2f(st[3]*CE);
        f32x4 a = {e0*irs, e1*irs, e2*irs, e3*irs};
        av[half*2 + sub] = a;
        bf16x4 pk = {f2bf(e0*ir), f2bf(e1*ir), f2bf(e2*ir), f2bf(e3*ir)};
        // P row = q(l16), col = s within 32-half (sub*16 + quad*4)
        *(bf16x4*)(&Pmine[l16*PW + sub*16 + quad*4]) = pk;
      }
      // PV for this 32-s half: A = P (q rows), B = V (d rows), 4 d-tiles
      bf16x8 a01 = *(const bf16x8*)(&Pmine[l16*PW + quad*8]);
      #pragma unroll
      for (int dt = 0; dt < 4; ++dt){
        const short* vp = vbase + (size_t)(dt*16)*LQ + win*64 + half*32;
        bf16x8 vf = *(const bf16x8*)vp;
        oacc[dt] = __builtin_amdgcn_mfma_f32_16x16x32_bf16(a01, vf, oacc[dt], 0, 0, 0);
      }
    }
    // stage this wave's attn window tile (q=l16 row, 4x f32x4)
    #pragma unroll
    for (int k = 0; k < 4; ++k)
      *(f32x4*)(&Amine[l16*AW + k*16 + quad*4]) = av[k];
    __syncthreads();
    // cross-head reduce + coalesced write: thread -> (q = tid>>6, s = tid&63)
    {
      int q = tid >> 6;
      int s = tid & 63;
      float sum = 0.f;
      #pragma unroll
      for (int ww = 0; ww < NH; ++ww)
        sum += astage[(size_t)ww*16*AW + q*AW + s];
      attn[((size_t)(n*LQ + q0 + q))*LQ + win*64 + s] = sum;
    }
    __syncthreads();
  }

  // ---- O store: row q0+quad*4+j, col w*64 + dt*16 + l16 ----
  #pragma unroll
  for (int dt = 0; dt < 4; ++dt){
    float* op = out + ((size_t)(n*LQ + q0 + quad*4))*DM + w*DH + dt*16 + l16;
    op[0]      = oacc[dt][0];
    op[DM]     = oacc[dt][1];
    op[2*DM]   = oacc[dt][2];
    op[3*DM]   = oacc[dt][3];
  }
}

extern "C" void kernel_launch(void* const* d_in, const int* in_sizes, int n_in,
                              void* d_out, int out_size, void* d_ws, size_t ws_size,
                              hipStream_t stream){
  const float* in = (const float*)d_in[0];
  float* out  = (float*)d_out;
  float* attn = out + (size_t)NB*LQ*DM;
  short* bN = (short*)d_ws;
  short* bT = bN + (size_t)NB*LQ*DM;

  k0_convert<<<dim3(8192), dim3(256),  0, stream>>>(in, bN, bT);
  k2_attn   <<<dim3(512),  dim3(1024), 0, stream>>>(bN, bT, out, attn);
}